// Round 1
// baseline (806.260 us; speedup 1.0000x reference)
//
#include <hip/hip_runtime.h>
#include <hip/hip_bf16.h>

#define NN 10000
#define EE 160000
#define DD 512
#define GG 64
#define OUTC 128

typedef __attribute__((ext_vector_type(8))) short bf16x8;
typedef __attribute__((ext_vector_type(4))) float f32x4;

static __device__ __forceinline__ unsigned short f2bf(float f) {
  unsigned u = __builtin_bit_cast(unsigned, f);
  unsigned rounding = 0x7fffu + ((u >> 16) & 1u);
  u += rounding;
  return (unsigned short)(u >> 16);
}
static __device__ __forceinline__ float bf2f(unsigned short h) {
  unsigned v = ((unsigned)h) << 16;
  return __builtin_bit_cast(float, v);
}

// ---------------- CSR build ----------------
__global__ void hist_dst(const int* __restrict__ dst, int* __restrict__ cnt) {
  int e = blockIdx.x * 256 + threadIdx.x;
  if (e < EE) atomicAdd(&cnt[dst[e]], 1);
}

__global__ void scan_offsets(const int* __restrict__ cnt, int* __restrict__ offs) {
  __shared__ int sdata[1024];
  __shared__ int carry;
  int t = threadIdx.x;
  if (t == 0) carry = 0;
  __syncthreads();
  for (int base = 0; base < NN; base += 1024) {
    int i = base + t;
    int v = (i < NN) ? cnt[i] : 0;
    sdata[t] = v;
    __syncthreads();
    for (int off = 1; off < 1024; off <<= 1) {
      int x = (t >= off) ? sdata[t - off] : 0;
      __syncthreads();
      sdata[t] += x;
      __syncthreads();
    }
    int incl = sdata[t];
    int c = carry;
    if (i < NN) offs[i] = c + incl - v;   // exclusive prefix
    __syncthreads();
    if (t == 0) carry += sdata[1023];
    __syncthreads();
  }
  if (t == 0) offs[NN] = carry;           // == EE
}

__global__ void fill_edges(const int* __restrict__ src, const int* __restrict__ dst,
                           const int* __restrict__ offs, int* __restrict__ fptr,
                           int* __restrict__ ssrc) {
  int e = blockIdx.x * 256 + threadIdx.x;
  if (e < EE) {
    int d = dst[e];
    int p = atomicAdd(&fptr[d], 1);
    ssrc[offs[d] + p] = src[e];
  }
}

// ---------------- weight transpose + bf16 convert ----------------
// W [512][512] f32 row-major  ->  WT [n][k] bf16 (K-major for MFMA B frags)
__global__ void transpose_w(const float* __restrict__ W, unsigned short* __restrict__ WT) {
  __shared__ float tile[32][33];
  int bx = blockIdx.x * 32, by = blockIdx.y * 32;
  int tx = threadIdx.x, ty = threadIdx.y;
  for (int i = ty; i < 32; i += 8)
    tile[i][tx] = W[(size_t)(by + i) * DD + bx + tx];
  __syncthreads();
  for (int i = ty; i < 32; i += 8)
    WT[(size_t)(bx + i) * DD + by + tx] = f2bf(tile[tx][i]);
}

// ---------------- x convert ----------------
__global__ void convert_x(const float* __restrict__ x, float* __restrict__ xf,
                          unsigned short* __restrict__ xb) {
  int i = blockIdx.x * 256 + threadIdx.x;   // pair index
  if (i < NN * DD / 2) {
    float2 v = ((const float2*)x)[i];
    ((float2*)xf)[i] = v;
    unsigned u = (unsigned)f2bf(v.x) | ((unsigned)f2bf(v.y) << 16);
    ((unsigned*)xb)[i] = u;
  }
}

// ---------------- segment sum (gather over CSR) ----------------
__global__ __launch_bounds__(256) void seg_sum(const unsigned short* __restrict__ xb,
                                               const int* __restrict__ offs,
                                               const int* __restrict__ ssrc,
                                               unsigned short* __restrict__ aggb) {
  int node = blockIdx.x;
  int t = threadIdx.x;                      // 256 threads, 2 bf16 cols each
  int beg = offs[node], end = offs[node + 1];
  const unsigned* xw = (const unsigned*)xb;
  float a0 = 0.f, a1 = 0.f;
  for (int e = beg; e < end; ++e) {
    int s = ssrc[e];
    unsigned v = xw[(size_t)s * (DD / 2) + t];
    a0 += bf2f((unsigned short)(v & 0xffffu));
    a1 += bf2f((unsigned short)(v >> 16));
  }
  unsigned u = (unsigned)f2bf(a0) | ((unsigned)f2bf(a1) << 16);
  ((unsigned*)aggb)[(size_t)node * (DD / 2) + t] = u;
}

// ---------------- fused layer GEMM: relu(xf + aggb@Wr + b + xb@Ws) ----------------
__global__ __launch_bounds__(256) void gemm_layer(
    const unsigned short* __restrict__ Abf,   // agg bf16 [NN][512]
    const unsigned short* __restrict__ Xbf,   // x   bf16 [NN][512]
    const unsigned short* __restrict__ WrT,   // [n][k] bf16
    const unsigned short* __restrict__ WsT,   // [n][k] bf16
    const float* __restrict__ bias,
    float* __restrict__ xf,                   // fp32 master, in-place residual
    unsigned short* __restrict__ xbf_out,     // next layer's bf16 x
    int do_relu) {
  int tid = threadIdx.x;
  int lane = tid & 63;
  int wave = tid >> 6;
  int wr = wave >> 1, wc = wave & 1;
  int row0 = blockIdx.x * 128 + wr * 64;
  int col0 = blockIdx.y * 128 + wc * 64;
  int lrow = lane & 15;
  int kq = (lane >> 4) * 8;

  f32x4 acc[4][4];
#pragma unroll
  for (int m = 0; m < 4; ++m)
#pragma unroll
    for (int n = 0; n < 4; ++n) acc[m][n] = (f32x4){0.f, 0.f, 0.f, 0.f};

  size_t arow[4];
#pragma unroll
  for (int m = 0; m < 4; ++m) {
    int r = row0 + m * 16 + lrow;
    if (r >= NN) r = 0;                       // clamp; OOB rows never stored
    arow[m] = (size_t)r * DD;
  }
  size_t bcol[4];
#pragma unroll
  for (int n = 0; n < 4; ++n) bcol[n] = (size_t)(col0 + n * 16 + lrow) * DD;

#pragma unroll 1
  for (int pass = 0; pass < 2; ++pass) {
    const unsigned short* A = pass ? Xbf : Abf;
    const unsigned short* B = pass ? WsT : WrT;
#pragma unroll 2
    for (int k0 = 0; k0 < DD; k0 += 32) {
      bf16x8 a[4], b[4];
#pragma unroll
      for (int m = 0; m < 4; ++m)
        a[m] = *(const bf16x8*)(A + arow[m] + k0 + kq);
#pragma unroll
      for (int n = 0; n < 4; ++n)
        b[n] = *(const bf16x8*)(B + bcol[n] + k0 + kq);
#pragma unroll
      for (int m = 0; m < 4; ++m)
#pragma unroll
        for (int n = 0; n < 4; ++n)
          acc[m][n] = __builtin_amdgcn_mfma_f32_16x16x32_bf16(a[m], b[n], acc[m][n], 0, 0, 0);
    }
  }

  // epilogue: C row=(lane>>4)*4+i, col=lane&15 within each 16x16 fragment
  int crow = (lane >> 4) * 4;
  int ccol = lane & 15;
#pragma unroll
  for (int m = 0; m < 4; ++m) {
#pragma unroll
    for (int n = 0; n < 4; ++n) {
      int col = col0 + n * 16 + ccol;
      float bv = bias[col];
#pragma unroll
      for (int i = 0; i < 4; ++i) {
        int row = row0 + m * 16 + crow + i;
        if (row < NN) {
          size_t idx = (size_t)row * DD + col;
          float v = acc[m][n][i] + bv + xf[idx];
          if (do_relu) v = fmaxf(v, 0.f);
          xf[idx] = v;
          xbf_out[idx] = f2bf(v);
        }
      }
    }
  }
}

// ---------------- pooling ----------------
__global__ void hist_batch(const int* __restrict__ batch, int* __restrict__ gcnt) {
  int i = blockIdx.x * 256 + threadIdx.x;
  if (i < NN) atomicAdd(&gcnt[batch[i]], 1);
}

__global__ void graph_starts(const int* __restrict__ gcnt, int* __restrict__ gstart) {
  int t = threadIdx.x;
  if (t <= GG) {
    int s = 0;
    for (int j = 0; j < t; ++j) s += gcnt[j];
    gstart[t] = s;
  }
}

__global__ __launch_bounds__(256) void pool_mean(const float* __restrict__ xf,
                                                 const int* __restrict__ gstart,
                                                 float* __restrict__ pooled) {
  int g = blockIdx.x;
  int t = threadIdx.x;
  int beg = gstart[g], end = gstart[g + 1];
  float a0 = 0.f, a1 = 0.f;
  for (int r = beg; r < end; ++r) {
    a0 += xf[(size_t)r * DD + t];
    a1 += xf[(size_t)r * DD + t + 256];
  }
  float inv = 1.0f / fmaxf((float)(end - beg), 1.0f);
  pooled[g * DD + t] = a0 * inv;
  pooled[g * DD + t + 256] = a1 * inv;
}

__global__ __launch_bounds__(128) void final_linear(const float* __restrict__ pooled,
                                                    const float* __restrict__ Wlin,
                                                    const float* __restrict__ blin,
                                                    float* __restrict__ out) {
  __shared__ float p[DD];
  int g = blockIdx.x;
  int o = threadIdx.x;
  for (int i = o; i < DD; i += 128) p[i] = pooled[g * DD + i];
  __syncthreads();
  float s = blin[o];
#pragma unroll 4
  for (int k = 0; k < DD; ++k) s += p[k] * Wlin[(size_t)k * OUTC + o];
  out[g * OUTC + o] = s;
}

// ---------------- host ----------------
extern "C" void kernel_launch(void* const* d_in, const int* in_sizes, int n_in,
                              void* d_out, int out_size, void* d_ws, size_t ws_size,
                              hipStream_t stream) {
  const float* x_in = (const float*)d_in[0];
  const int* ei = (const int*)d_in[1];
  const int* src = ei;
  const int* dst = ei + EE;
  const int* batch = (const int*)d_in[2];
  const float* Wr[5], *Ws[5], *bias[5];
  for (int l = 0; l < 5; ++l) {
    Wr[l] = (const float*)d_in[3 + 3 * l];
    Ws[l] = (const float*)d_in[4 + 3 * l];
    bias[l] = (const float*)d_in[5 + 3 * l];
  }
  const float* Wlin = (const float*)d_in[18];
  const float* blin = (const float*)d_in[19];
  float* out = (float*)d_out;

  char* ws = (char*)d_ws;
  size_t off = 0;
  auto alloc = [&](size_t bytes) { size_t o = off; off += (bytes + 511) & ~(size_t)511; return o; };
  float* xf = (float*)(ws + alloc((size_t)NN * DD * 4));
  unsigned short* xb0 = (unsigned short*)(ws + alloc((size_t)NN * DD * 2));
  unsigned short* xb1 = (unsigned short*)(ws + alloc((size_t)NN * DD * 2));
  unsigned short* aggb = (unsigned short*)(ws + alloc((size_t)NN * DD * 2));
  unsigned short* wt = (unsigned short*)(ws + alloc((size_t)10 * DD * DD * 2));
  int* deg = (int*)(ws + alloc((size_t)NN * 4));
  int* offs = (int*)(ws + alloc((size_t)(NN + 1) * 4));
  int* fptr = (int*)(ws + alloc((size_t)NN * 4));
  int* ssrc = (int*)(ws + alloc((size_t)EE * 4));
  int* gcnt = (int*)(ws + alloc((size_t)GG * 4));
  int* gstart = (int*)(ws + alloc((size_t)(GG + 1) * 4));
  float* pooled = (float*)(ws + alloc((size_t)GG * DD * 4));

  hipMemsetAsync(deg, 0, (size_t)NN * 4, stream);
  hipMemsetAsync(fptr, 0, (size_t)NN * 4, stream);
  hipMemsetAsync(gcnt, 0, (size_t)GG * 4, stream);

  // CSR
  int eblocks = (EE + 255) / 256;
  hist_dst<<<eblocks, 256, 0, stream>>>(dst, deg);
  scan_offsets<<<1, 1024, 0, stream>>>(deg, offs);
  fill_edges<<<eblocks, 256, 0, stream>>>(src, dst, offs, fptr, ssrc);

  // weights -> transposed bf16
  dim3 tb(32, 8), tg(DD / 32, DD / 32);
  for (int l = 0; l < 5; ++l) {
    transpose_w<<<tg, tb, 0, stream>>>(Wr[l], wt + (size_t)(2 * l) * DD * DD);
    transpose_w<<<tg, tb, 0, stream>>>(Ws[l], wt + (size_t)(2 * l + 1) * DD * DD);
  }

  // x -> fp32 master + bf16
  convert_x<<<(NN * DD / 2 + 255) / 256, 256, 0, stream>>>(x_in, xf, xb0);

  // layers
  unsigned short* xb_cur = xb0;
  unsigned short* xb_nxt = xb1;
  dim3 ggrid((NN + 127) / 128, DD / 128);
  for (int l = 0; l < 5; ++l) {
    seg_sum<<<NN, 256, 0, stream>>>(xb_cur, offs, ssrc, aggb);
    gemm_layer<<<ggrid, 256, 0, stream>>>(aggb, xb_cur,
                                          wt + (size_t)(2 * l) * DD * DD,
                                          wt + (size_t)(2 * l + 1) * DD * DD,
                                          bias[l], xf, xb_nxt, l < 4 ? 1 : 0);
    unsigned short* t = xb_cur; xb_cur = xb_nxt; xb_nxt = t;
  }

  // pooling + final linear
  hist_batch<<<(NN + 255) / 256, 256, 0, stream>>>(batch, gcnt);
  graph_starts<<<1, 128, 0, stream>>>(gcnt, gstart);
  pool_mean<<<GG, 256, 0, stream>>>(xf, gstart, pooled);
  final_linear<<<GG, 128, 0, stream>>>(pooled, Wlin, blin, out);
}

// Round 2
// 474.650 us; speedup vs baseline: 1.6986x; 1.6986x over previous
//
#include <hip/hip_runtime.h>
#include <hip/hip_bf16.h>

#define NN 10000
#define EE 160000
#define DD 512
#define GG 64
#define OUTC 128

typedef __attribute__((ext_vector_type(8))) short bf16x8;
typedef __attribute__((ext_vector_type(4))) float f32x4;

static __device__ __forceinline__ unsigned short f2bf(float f) {
  unsigned u = __builtin_bit_cast(unsigned, f);
  unsigned rounding = 0x7fffu + ((u >> 16) & 1u);
  u += rounding;
  return (unsigned short)(u >> 16);
}
static __device__ __forceinline__ float bf2f(unsigned short h) {
  unsigned v = ((unsigned)h) << 16;
  return __builtin_bit_cast(float, v);
}

static __device__ __forceinline__ void gload_lds16(const void* g, void* l) {
  __builtin_amdgcn_global_load_lds(
      (const __attribute__((address_space(1))) unsigned*)g,
      (__attribute__((address_space(3))) unsigned*)l, 16, 0, 0);
}

// ---------------- CSR build ----------------
__global__ void hist_dst(const int* __restrict__ dst, int* __restrict__ cnt) {
  int e = blockIdx.x * 256 + threadIdx.x;
  if (e < EE) atomicAdd(&cnt[dst[e]], 1);
}

__global__ void scan_offsets(const int* __restrict__ cnt, int* __restrict__ offs) {
  __shared__ int wpre[17];
  __shared__ int carry;
  int t = threadIdx.x;            // 1024 threads = 16 waves
  int lane = t & 63, wv = t >> 6;
  if (t == 0) carry = 0;
  __syncthreads();
  for (int base = 0; base < NN; base += 1024) {
    int i = base + t;
    int v = (i < NN) ? cnt[i] : 0;
    int s = v;
#pragma unroll
    for (int d = 1; d < 64; d <<= 1) {
      int o = __shfl_up(s, d, 64);
      if (lane >= d) s += o;
    }
    if (lane == 63) wpre[wv] = s;
    __syncthreads();
    if (t == 0) {
      int r = 0;
      for (int w = 0; w < 16; ++w) { int x = wpre[w]; wpre[w] = r; r += x; }
      wpre[16] = r;
    }
    __syncthreads();
    int incl = s + wpre[wv] + carry;
    if (i < NN) offs[i] = incl - v;   // exclusive prefix
    __syncthreads();
    if (t == 0) carry += wpre[16];
    __syncthreads();
  }
  if (t == 0) offs[NN] = carry;       // == EE
}

__global__ void fill_edges(const int* __restrict__ src, const int* __restrict__ dst,
                           const int* __restrict__ offs, int* __restrict__ fptr,
                           int* __restrict__ ssrc) {
  int e = blockIdx.x * 256 + threadIdx.x;
  if (e < EE) {
    int d = dst[e];
    int p = atomicAdd(&fptr[d], 1);
    ssrc[offs[d] + p] = src[e];
  }
}

// ---------------- weight transpose + bf16 convert (all 10 in one dispatch) ----
// W [512 k][512 n] f32 row-major -> WT merged [layer][512 n][1024 k] bf16
// Wr occupies k 0..511, Ws occupies k 512..1023
struct WPtrs { const float* p[10]; };

__global__ void transpose_w_all(WPtrs wp, unsigned short* __restrict__ WT) {
  __shared__ float tile[32][33];
  int z = blockIdx.z;                 // 0..9: layer z>>1, (z&1)=Ws
  const float* W = wp.p[z];
  unsigned short* dst = WT + (size_t)(z >> 1) * DD * 1024 + (size_t)(z & 1) * DD;
  int bx = blockIdx.x * 32, by = blockIdx.y * 32;
  int tx = threadIdx.x, ty = threadIdx.y;
  for (int i = ty; i < 32; i += 8)
    tile[i][tx] = W[(size_t)(by + i) * DD + bx + tx];
  __syncthreads();
  for (int i = ty; i < 32; i += 8)
    dst[(size_t)(bx + i) * 1024 + by + tx] = f2bf(tile[tx][i]);
}

// ---------------- x convert: fp32 master + bf16 into merged0 right half ------
__global__ void convert_x(const float* __restrict__ x, float* __restrict__ xf,
                          unsigned short* __restrict__ m0) {
  int i = blockIdx.x * 256 + threadIdx.x;   // pair index
  if (i < NN * DD / 2) {
    float2 v = ((const float2*)x)[i];
    ((float2*)xf)[i] = v;
    unsigned u = (unsigned)f2bf(v.x) | ((unsigned)f2bf(v.y) << 16);
    int e = i << 1;
    int row = e >> 9, col = e & 511;
    ((unsigned*)m0)[row * 512 + 256 + (col >> 1)] = u;
  }
}

// ---------------- segment sum: wave per node, 16B lanes, 4-edge ILP ----------
// merged layout per row: [agg(512) | x(512)] bf16.  Reads right half of
// gathered rows, writes left half of own row.
static __device__ __forceinline__ void acc8(float* a, uint4 v) {
  unsigned w0 = v.x, w1 = v.y, w2 = v.z, w3 = v.w;
  a[0] += __builtin_bit_cast(float, w0 << 16);
  a[1] += __builtin_bit_cast(float, w0 & 0xffff0000u);
  a[2] += __builtin_bit_cast(float, w1 << 16);
  a[3] += __builtin_bit_cast(float, w1 & 0xffff0000u);
  a[4] += __builtin_bit_cast(float, w2 << 16);
  a[5] += __builtin_bit_cast(float, w2 & 0xffff0000u);
  a[6] += __builtin_bit_cast(float, w3 << 16);
  a[7] += __builtin_bit_cast(float, w3 & 0xffff0000u);
}

__global__ __launch_bounds__(256) void seg_sum(unsigned short* __restrict__ merged,
                                               const int* __restrict__ offs,
                                               const int* __restrict__ ssrc) {
  int node = (blockIdx.x << 2) + (threadIdx.x >> 6);
  if (node >= NN) return;
  int lane = threadIdx.x & 63;
  int beg = offs[node], end = offs[node + 1];
  const uint4* xb = (const uint4*)merged;   // row = 128 uint4; right half at +64
  float a[8] = {0.f, 0.f, 0.f, 0.f, 0.f, 0.f, 0.f, 0.f};
  int e = beg;
  for (; e + 4 <= end; e += 4) {
    int s0 = ssrc[e], s1 = ssrc[e + 1], s2 = ssrc[e + 2], s3 = ssrc[e + 3];
    uint4 v0 = xb[(size_t)s0 * 128 + 64 + lane];
    uint4 v1 = xb[(size_t)s1 * 128 + 64 + lane];
    uint4 v2 = xb[(size_t)s2 * 128 + 64 + lane];
    uint4 v3 = xb[(size_t)s3 * 128 + 64 + lane];
    acc8(a, v0); acc8(a, v1); acc8(a, v2); acc8(a, v3);
  }
  for (; e < end; ++e) {
    uint4 v = xb[(size_t)ssrc[e] * 128 + 64 + lane];
    acc8(a, v);
  }
  uint4 o;
  o.x = (unsigned)f2bf(a[0]) | ((unsigned)f2bf(a[1]) << 16);
  o.y = (unsigned)f2bf(a[2]) | ((unsigned)f2bf(a[3]) << 16);
  o.z = (unsigned)f2bf(a[4]) | ((unsigned)f2bf(a[5]) << 16);
  o.w = (unsigned)f2bf(a[6]) | ((unsigned)f2bf(a[7]) << 16);
  ((uint4*)merged)[(size_t)node * 128 + lane] = o;
}

// ---------------- fused layer GEMM --------------------------------------
// C[row,col] = sum_k merged[row][k] * WT[col][k]   (k = 0..1023 covers both
// agg@Wr and x@Ws), then + bias + xf residual, ReLU, write xf (fp32 master)
// and bf16 into NEXT merged buffer's right half.
// 128x128 tile, BK=64, double-buffered LDS staged via global_load_lds(16B)
// with XOR chunk swizzle (chunk ^= row&7) applied to global src AND ds_read.
__global__ __launch_bounds__(256) void gemm_layer(
    const unsigned short* __restrict__ Am,    // merged cur [NN][1024]
    const unsigned short* __restrict__ Bw,    // [512 n][1024 k]
    const float* __restrict__ bias,
    float* __restrict__ xf,
    unsigned short* __restrict__ xout,        // merged next (write right half)
    int do_relu) {
  __shared__ unsigned short Al[2][128 * 64];
  __shared__ unsigned short Bl[2][128 * 64];
  int tid = threadIdx.x;
  int lane = tid & 63, wave = tid >> 6;
  int wr = wave >> 1, wc = wave & 1;
  int brow = blockIdx.x * 128;
  int bcol = blockIdx.y * 128;
  int lrow = lane & 15, lq = lane >> 4;

  f32x4 acc[4][4];
#pragma unroll
  for (int m = 0; m < 4; ++m)
#pragma unroll
    for (int n = 0; n < 4; ++n) acc[m][n] = (f32x4){0.f, 0.f, 0.f, 0.f};

  auto STAGE = [&](int buf, int t) {
    int k0 = t * 64;
#pragma unroll
    for (int i = 0; i < 4; ++i) {
      int idx = i * 256 + tid;
      int row = idx >> 3, c = idx & 7;
      int csw = (c ^ (row & 7)) * 8;
      int gr = brow + row;
      if (gr >= NN) gr = NN - 1;            // clamp; OOB rows never stored
      gload_lds16(Am + (size_t)gr * 1024 + k0 + csw, &Al[buf][idx * 8]);
    }
#pragma unroll
    for (int i = 0; i < 4; ++i) {
      int idx = i * 256 + tid;
      int row = idx >> 3, c = idx & 7;
      int csw = (c ^ (row & 7)) * 8;
      gload_lds16(Bw + (size_t)(bcol + row) * 1024 + k0 + csw, &Bl[buf][idx * 8]);
    }
  };

  STAGE(0, 0);
  __syncthreads();                            // drains vmcnt(0): buf0 ready
  int cur = 0;
#pragma unroll 1
  for (int t = 0; t < 16; ++t) {
    if (t < 15) STAGE(cur ^ 1, t + 1);        // in flight under compute
#pragma unroll
    for (int kk = 0; kk < 2; ++kk) {
      bf16x8 a[4], b[4];
      int lc = kk * 4 + lq;                   // logical 16B chunk 0..7
#pragma unroll
      for (int m = 0; m < 4; ++m) {
        int row = wr * 64 + m * 16 + lrow;
        a[m] = *(const bf16x8*)&Al[cur][row * 64 + ((lc ^ (lrow & 7)) * 8)];
      }
#pragma unroll
      for (int n = 0; n < 4; ++n) {
        int row = wc * 64 + n * 16 + lrow;
        b[n] = *(const bf16x8*)&Bl[cur][row * 64 + ((lc ^ (lrow & 7)) * 8)];
      }
#pragma unroll
      for (int m = 0; m < 4; ++m)
#pragma unroll
        for (int n = 0; n < 4; ++n)
          acc[m][n] = __builtin_amdgcn_mfma_f32_16x16x32_bf16(a[m], b[n], acc[m][n], 0, 0, 0);
    }
    __syncthreads();                          // compute done; next buf staged
    cur ^= 1;
  }

  // epilogue: C row=(lane>>4)*4+i, col=lane&15 within each 16x16 fragment
  int crow = (lane >> 4) * 4;
  int ccol = lane & 15;
#pragma unroll
  for (int m = 0; m < 4; ++m) {
#pragma unroll
    for (int n = 0; n < 4; ++n) {
      int col = bcol + wc * 64 + n * 16 + ccol;
      float bv = bias[col];
#pragma unroll
      for (int i = 0; i < 4; ++i) {
        int row = brow + wr * 64 + m * 16 + crow + i;
        if (row < NN) {
          size_t idx = (size_t)row * DD + col;
          float v = acc[m][n][i] + bv + xf[idx];
          if (do_relu) v = fmaxf(v, 0.f);
          xf[idx] = v;
          xout[(size_t)row * 1024 + 512 + col] = f2bf(v);
        }
      }
    }
  }
}

// ---------------- pooling ----------------
__global__ void hist_batch(const int* __restrict__ batch, int* __restrict__ gcnt) {
  int i = blockIdx.x * 256 + threadIdx.x;
  if (i < NN) atomicAdd(&gcnt[batch[i]], 1);
}

__global__ void graph_starts(const int* __restrict__ gcnt, int* __restrict__ gstart) {
  int t = threadIdx.x;
  if (t <= GG) {
    int s = 0;
    for (int j = 0; j < t; ++j) s += gcnt[j];
    gstart[t] = s;
  }
}

__global__ __launch_bounds__(256) void pool_partial(const float* __restrict__ xf,
                                                    const int* __restrict__ gstart,
                                                    float* __restrict__ pooled) {
  int g = blockIdx.x, part = blockIdx.y;    // 4 parts per graph
  int t = threadIdx.x;
  int beg = gstart[g], end = gstart[g + 1];
  int n = end - beg;
  int per = (n + 3) >> 2;
  int b = beg + part * per;
  int e = b + per; if (e > end) e = end;
  if (b >= e) return;
  float a0 = 0.f, a1 = 0.f;
  for (int r = b; r < e; ++r) {
    a0 += xf[(size_t)r * DD + t];
    a1 += xf[(size_t)r * DD + t + 256];
  }
  atomicAdd(&pooled[g * DD + t], a0);
  atomicAdd(&pooled[g * DD + t + 256], a1);
}

__global__ __launch_bounds__(128) void final_linear(const float* __restrict__ pooled,
                                                    const int* __restrict__ gcnt,
                                                    const float* __restrict__ Wlin,
                                                    const float* __restrict__ blin,
                                                    float* __restrict__ out) {
  __shared__ float p[DD];
  int g = blockIdx.x;
  int o = threadIdx.x;
  float inv = 1.0f / fmaxf((float)gcnt[g], 1.0f);
  for (int i = o; i < DD; i += 128) p[i] = pooled[g * DD + i] * inv;
  __syncthreads();
  float s = blin[o];
#pragma unroll 4
  for (int k = 0; k < DD; ++k) s += p[k] * Wlin[(size_t)k * OUTC + o];
  out[g * OUTC + o] = s;
}

// ---------------- host ----------------
extern "C" void kernel_launch(void* const* d_in, const int* in_sizes, int n_in,
                              void* d_out, int out_size, void* d_ws, size_t ws_size,
                              hipStream_t stream) {
  const float* x_in = (const float*)d_in[0];
  const int* ei = (const int*)d_in[1];
  const int* src = ei;
  const int* dst = ei + EE;
  const int* batch = (const int*)d_in[2];
  WPtrs wp;
  const float* bias[5];
  for (int l = 0; l < 5; ++l) {
    wp.p[2 * l] = (const float*)d_in[3 + 3 * l];      // Wr
    wp.p[2 * l + 1] = (const float*)d_in[4 + 3 * l];  // Ws
    bias[l] = (const float*)d_in[5 + 3 * l];
  }
  const float* Wlin = (const float*)d_in[18];
  const float* blin = (const float*)d_in[19];
  float* out = (float*)d_out;

  char* ws = (char*)d_ws;
  size_t off = 0;
  auto alloc = [&](size_t bytes) { size_t o = off; off += (bytes + 511) & ~(size_t)511; return o; };
  float* xf = (float*)(ws + alloc((size_t)NN * DD * 4));
  unsigned short* m0 = (unsigned short*)(ws + alloc((size_t)NN * 1024 * 2));
  unsigned short* m1 = (unsigned short*)(ws + alloc((size_t)NN * 1024 * 2));
  unsigned short* wt = (unsigned short*)(ws + alloc((size_t)5 * DD * 1024 * 2));
  int* deg = (int*)(ws + alloc((size_t)NN * 4));
  int* offs = (int*)(ws + alloc((size_t)(NN + 1) * 4));
  int* fptr = (int*)(ws + alloc((size_t)NN * 4));
  int* ssrc = (int*)(ws + alloc((size_t)EE * 4));
  int* gcnt = (int*)(ws + alloc((size_t)GG * 4));
  int* gstart = (int*)(ws + alloc((size_t)(GG + 1) * 4));
  float* pooled = (float*)(ws + alloc((size_t)GG * DD * 4));

  hipMemsetAsync(deg, 0, (size_t)NN * 4, stream);
  hipMemsetAsync(fptr, 0, (size_t)NN * 4, stream);
  hipMemsetAsync(gcnt, 0, (size_t)GG * 4, stream);
  hipMemsetAsync(pooled, 0, (size_t)GG * DD * 4, stream);

  // CSR
  int eblocks = (EE + 255) / 256;
  hist_dst<<<eblocks, 256, 0, stream>>>(dst, deg);
  scan_offsets<<<1, 1024, 0, stream>>>(deg, offs);
  fill_edges<<<eblocks, 256, 0, stream>>>(src, dst, offs, fptr, ssrc);

  // weights -> merged transposed bf16 (single dispatch)
  dim3 tb(32, 8), tg(DD / 32, DD / 32, 10);
  transpose_w_all<<<tg, tb, 0, stream>>>(wp, wt);

  // x -> fp32 master + bf16 right half of merged0
  convert_x<<<(NN * DD / 2 + 255) / 256, 256, 0, stream>>>(x_in, xf, m0);

  // batch histogram (independent of layers)
  hist_batch<<<(NN + 255) / 256, 256, 0, stream>>>(batch, gcnt);
  graph_starts<<<1, 128, 0, stream>>>(gcnt, gstart);

  // layers
  dim3 ggrid((NN + 127) / 128, DD / 128);
  unsigned short* mc = m0;
  unsigned short* mn = m1;
  for (int l = 0; l < 5; ++l) {
    seg_sum<<<(NN + 3) / 4, 256, 0, stream>>>(mc, offs, ssrc);
    gemm_layer<<<ggrid, 256, 0, stream>>>(mc, wt + (size_t)l * DD * 1024,
                                          bias[l], xf, mn, l < 4 ? 1 : 0);
    unsigned short* t = mc; mc = mn; mn = t;
  }

  // pooling + final linear
  dim3 pgrid(GG, 4);
  pool_partial<<<pgrid, 256, 0, stream>>>(xf, gstart, pooled);
  final_linear<<<GG, 128, 0, stream>>>(pooled, gcnt, Wlin, blin, out);
}

// Round 3
// 393.526 us; speedup vs baseline: 2.0488x; 1.2061x over previous
//
#include <hip/hip_runtime.h>
#include <hip/hip_bf16.h>

#define NN 10000
#define EE 160000
#define DD 512
#define GG 64
#define OUTC 128

typedef __attribute__((ext_vector_type(8))) short bf16x8;
typedef __attribute__((ext_vector_type(4))) float f32x4;

static __device__ __forceinline__ unsigned short f2bf(float f) {
  unsigned u = __builtin_bit_cast(unsigned, f);
  unsigned rounding = 0x7fffu + ((u >> 16) & 1u);
  u += rounding;
  return (unsigned short)(u >> 16);
}
static __device__ __forceinline__ float bf2f(unsigned short h) {
  unsigned v = ((unsigned)h) << 16;
  return __builtin_bit_cast(float, v);
}

static __device__ __forceinline__ void gload_lds16(const void* g, void* l) {
  __builtin_amdgcn_global_load_lds(
      (const __attribute__((address_space(1))) unsigned*)g,
      (__attribute__((address_space(3))) unsigned*)l, 16, 0, 0);
}

// ---------------- CSR build ----------------
__global__ void hist_dst(const int* __restrict__ dst, int* __restrict__ cnt) {
  int e = blockIdx.x * 256 + threadIdx.x;
  if (e < EE) atomicAdd(&cnt[dst[e]], 1);
}

__global__ void scan_offsets(const int* __restrict__ cnt, int* __restrict__ offs) {
  __shared__ int wpre[17];
  __shared__ int carry;
  int t = threadIdx.x;            // 1024 threads = 16 waves
  int lane = t & 63, wv = t >> 6;
  if (t == 0) carry = 0;
  __syncthreads();
  for (int base = 0; base < NN; base += 1024) {
    int i = base + t;
    int v = (i < NN) ? cnt[i] : 0;
    int s = v;
#pragma unroll
    for (int d = 1; d < 64; d <<= 1) {
      int o = __shfl_up(s, d, 64);
      if (lane >= d) s += o;
    }
    if (lane == 63) wpre[wv] = s;
    __syncthreads();
    if (t == 0) {
      int r = 0;
      for (int w = 0; w < 16; ++w) { int x = wpre[w]; wpre[w] = r; r += x; }
      wpre[16] = r;
    }
    __syncthreads();
    int incl = s + wpre[wv] + carry;
    if (i < NN) offs[i] = incl - v;   // exclusive prefix
    __syncthreads();
    if (t == 0) carry += wpre[16];
    __syncthreads();
  }
  if (t == 0) offs[NN] = carry;       // == EE
}

__global__ void fill_edges(const int* __restrict__ src, const int* __restrict__ dst,
                           const int* __restrict__ offs, int* __restrict__ fptr,
                           int* __restrict__ ssrc) {
  int e = blockIdx.x * 256 + threadIdx.x;
  if (e < EE) {
    int d = dst[e];
    int p = atomicAdd(&fptr[d], 1);
    ssrc[offs[d] + p] = src[e];
  }
}

// ---------------- weight transpose + bf16 convert (all 10 in one dispatch) ----
// W [512 k][512 n] f32 row-major -> WT merged [layer][512 n][1024 k] bf16
// Wr occupies k 0..511, Ws occupies k 512..1023
struct WPtrs { const float* p[10]; };

__global__ void transpose_w_all(WPtrs wp, unsigned short* __restrict__ WT) {
  __shared__ float tile[32][33];
  int z = blockIdx.z;                 // 0..9: layer z>>1, (z&1)=Ws
  const float* W = wp.p[z];
  unsigned short* dst = WT + (size_t)(z >> 1) * DD * 1024 + (size_t)(z & 1) * DD;
  int bx = blockIdx.x * 32, by = blockIdx.y * 32;
  int tx = threadIdx.x, ty = threadIdx.y;
  for (int i = ty; i < 32; i += 8)
    tile[i][tx] = W[(size_t)(by + i) * DD + bx + tx];
  __syncthreads();
  for (int i = ty; i < 32; i += 8)
    dst[(size_t)(bx + i) * 1024 + by + tx] = f2bf(tile[tx][i]);
}

// ---------------- x convert: fp32 master + bf16 into merged0 right half ------
__global__ void convert_x(const float* __restrict__ x, float* __restrict__ xf,
                          unsigned short* __restrict__ m0) {
  int i = blockIdx.x * 256 + threadIdx.x;   // pair index
  if (i < NN * DD / 2) {
    float2 v = ((const float2*)x)[i];
    ((float2*)xf)[i] = v;
    unsigned u = (unsigned)f2bf(v.x) | ((unsigned)f2bf(v.y) << 16);
    int e = i << 1;
    int row = e >> 9, col = e & 511;
    ((unsigned*)m0)[row * 512 + 256 + (col >> 1)] = u;
  }
}

// ---------------- segment sum: wave per node, 16B lanes, 4-edge ILP ----------
// merged layout per row: [agg(512) | x(512)] bf16.  Reads right half of
// gathered rows, writes left half of own row.
static __device__ __forceinline__ void acc8(float* a, uint4 v) {
  unsigned w0 = v.x, w1 = v.y, w2 = v.z, w3 = v.w;
  a[0] += __builtin_bit_cast(float, w0 << 16);
  a[1] += __builtin_bit_cast(float, w0 & 0xffff0000u);
  a[2] += __builtin_bit_cast(float, w1 << 16);
  a[3] += __builtin_bit_cast(float, w1 & 0xffff0000u);
  a[4] += __builtin_bit_cast(float, w2 << 16);
  a[5] += __builtin_bit_cast(float, w2 & 0xffff0000u);
  a[6] += __builtin_bit_cast(float, w3 << 16);
  a[7] += __builtin_bit_cast(float, w3 & 0xffff0000u);
}

__global__ __launch_bounds__(256) void seg_sum(unsigned short* __restrict__ merged,
                                               const int* __restrict__ offs,
                                               const int* __restrict__ ssrc) {
  int node = (blockIdx.x << 2) + (threadIdx.x >> 6);
  if (node >= NN) return;
  int lane = threadIdx.x & 63;
  int beg = offs[node], end = offs[node + 1];
  const uint4* xb = (const uint4*)merged;   // row = 128 uint4; right half at +64
  float a[8] = {0.f, 0.f, 0.f, 0.f, 0.f, 0.f, 0.f, 0.f};
  int e = beg;
  for (; e + 4 <= end; e += 4) {
    int s0 = ssrc[e], s1 = ssrc[e + 1], s2 = ssrc[e + 2], s3 = ssrc[e + 3];
    uint4 v0 = xb[(size_t)s0 * 128 + 64 + lane];
    uint4 v1 = xb[(size_t)s1 * 128 + 64 + lane];
    uint4 v2 = xb[(size_t)s2 * 128 + 64 + lane];
    uint4 v3 = xb[(size_t)s3 * 128 + 64 + lane];
    acc8(a, v0); acc8(a, v1); acc8(a, v2); acc8(a, v3);
  }
  for (; e < end; ++e) {
    uint4 v = xb[(size_t)ssrc[e] * 128 + 64 + lane];
    acc8(a, v);
  }
  uint4 o;
  o.x = (unsigned)f2bf(a[0]) | ((unsigned)f2bf(a[1]) << 16);
  o.y = (unsigned)f2bf(a[2]) | ((unsigned)f2bf(a[3]) << 16);
  o.z = (unsigned)f2bf(a[4]) | ((unsigned)f2bf(a[5]) << 16);
  o.w = (unsigned)f2bf(a[6]) | ((unsigned)f2bf(a[7]) << 16);
  ((uint4*)merged)[(size_t)node * 128 + lane] = o;
}

// ---------------- fused layer GEMM --------------------------------------
// C[row,col] = sum_k merged[row][k] * WT[col][k]   (k = 0..1023 covers both
// agg@Wr and x@Ws), then + bias + xf residual, ReLU, write xf (fp32 master)
// and bf16 into NEXT merged buffer's right half.
// 128x128 tile, BK=64, double-buffered LDS staged via global_load_lds(16B)
// with XOR chunk swizzle (chunk ^= row&7) applied to global src AND ds_read.
__global__ __launch_bounds__(256) void gemm_layer(
    const unsigned short* __restrict__ Am,    // merged cur [NN][1024]
    const unsigned short* __restrict__ Bw,    // [512 n][1024 k]
    const float* __restrict__ bias,
    float* __restrict__ xf,
    unsigned short* __restrict__ xout,        // merged next (write right half)
    int do_relu) {
  __shared__ unsigned short Al[2][128 * 64];
  __shared__ unsigned short Bl[2][128 * 64];
  int tid = threadIdx.x;
  int lane = tid & 63, wave = tid >> 6;
  int wr = wave >> 1, wc = wave & 1;
  int brow = blockIdx.x * 128;
  int bcol = blockIdx.y * 128;
  int lrow = lane & 15, lq = lane >> 4;

  f32x4 acc[4][4];
#pragma unroll
  for (int m = 0; m < 4; ++m)
#pragma unroll
    for (int n = 0; n < 4; ++n) acc[m][n] = (f32x4){0.f, 0.f, 0.f, 0.f};

  auto STAGE = [&](int buf, int t) {
    int k0 = t * 64;
#pragma unroll
    for (int i = 0; i < 4; ++i) {
      int idx = i * 256 + tid;
      int row = idx >> 3, c = idx & 7;
      int csw = (c ^ (row & 7)) * 8;
      int gr = brow + row;
      if (gr >= NN) gr = NN - 1;            // clamp; OOB rows never stored
      gload_lds16(Am + (size_t)gr * 1024 + k0 + csw, &Al[buf][idx * 8]);
    }
#pragma unroll
    for (int i = 0; i < 4; ++i) {
      int idx = i * 256 + tid;
      int row = idx >> 3, c = idx & 7;
      int csw = (c ^ (row & 7)) * 8;
      gload_lds16(Bw + (size_t)(bcol + row) * 1024 + k0 + csw, &Bl[buf][idx * 8]);
    }
  };

  STAGE(0, 0);
  __syncthreads();                            // drains vmcnt(0): buf0 ready
  int cur = 0;
#pragma unroll 1
  for (int t = 0; t < 16; ++t) {
    if (t < 15) STAGE(cur ^ 1, t + 1);        // in flight under compute
#pragma unroll
    for (int kk = 0; kk < 2; ++kk) {
      bf16x8 a[4], b[4];
      int lc = kk * 4 + lq;                   // logical 16B chunk 0..7
#pragma unroll
      for (int m = 0; m < 4; ++m) {
        int row = wr * 64 + m * 16 + lrow;
        a[m] = *(const bf16x8*)&Al[cur][row * 64 + ((lc ^ (lrow & 7)) * 8)];
      }
#pragma unroll
      for (int n = 0; n < 4; ++n) {
        int row = wc * 64 + n * 16 + lrow;
        b[n] = *(const bf16x8*)&Bl[cur][row * 64 + ((lc ^ (lrow & 7)) * 8)];
      }
#pragma unroll
      for (int m = 0; m < 4; ++m)
#pragma unroll
        for (int n = 0; n < 4; ++n)
          acc[m][n] = __builtin_amdgcn_mfma_f32_16x16x32_bf16(a[m], b[n], acc[m][n], 0, 0, 0);
    }
    __syncthreads();                          // compute done; next buf staged
    cur ^= 1;
  }

  // epilogue: C row=(lane>>4)*4+i, col=lane&15 within each 16x16 fragment
  int crow = (lane >> 4) * 4;
  int ccol = lane & 15;
#pragma unroll
  for (int m = 0; m < 4; ++m) {
#pragma unroll
    for (int n = 0; n < 4; ++n) {
      int col = bcol + wc * 64 + n * 16 + ccol;
      float bv = bias[col];
#pragma unroll
      for (int i = 0; i < 4; ++i) {
        int row = brow + wr * 64 + m * 16 + crow + i;
        if (row < NN) {
          size_t idx = (size_t)row * DD + col;
          float v = acc[m][n][i] + bv + xf[idx];
          if (do_relu) v = fmaxf(v, 0.f);
          xf[idx] = v;
          xout[(size_t)row * 1024 + 512 + col] = f2bf(v);
        }
      }
    }
  }
}

// ---------------- pooling ----------------
// batch is sorted: find graph boundaries with disjoint writes (no atomics).
__global__ void graph_bounds(const int* __restrict__ batch, int* __restrict__ gstart) {
  int i = blockIdx.x * 256 + threadIdx.x;
  if (i >= NN) return;
  int cur = batch[i];
  int prev = (i == 0) ? -1 : batch[i - 1];
  for (int g = prev + 1; g <= cur; ++g) gstart[g] = i;
  if (i == NN - 1)
    for (int g = cur + 1; g <= GG; ++g) gstart[g] = NN;
}

// reads bf16 final x from merged right half (half the traffic of fp32 master)
__global__ __launch_bounds__(256) void pool_partial(const unsigned short* __restrict__ mfin,
                                                    const int* __restrict__ gstart,
                                                    float* __restrict__ pooled) {
  int g = blockIdx.x, part = blockIdx.y;    // 8 parts per graph
  int t = threadIdx.x;                      // 256 threads: col pair 2t,2t+1
  int beg = gstart[g], end = gstart[g + 1];
  int n = end - beg;
  int per = (n + 7) >> 3;
  int b = beg + part * per;
  int e = b + per; if (e > end) e = end;
  if (b >= e) return;
  const unsigned* mw = (const unsigned*)mfin;
  float a0 = 0.f, a1 = 0.f;
  for (int r = b; r < e; ++r) {
    unsigned v = mw[(size_t)r * 512 + 256 + t];
    a0 += __builtin_bit_cast(float, v << 16);
    a1 += __builtin_bit_cast(float, v & 0xffff0000u);
  }
  atomicAdd(&pooled[g * DD + 2 * t], a0);
  atomicAdd(&pooled[g * DD + 2 * t + 1], a1);
}

// grid (GG, 4): each block computes 128-k-slice partial of out[g][*]
__global__ __launch_bounds__(128) void final_linear(const float* __restrict__ pooled,
                                                    const int* __restrict__ gstart,
                                                    const float* __restrict__ Wlin,
                                                    const float* __restrict__ blin,
                                                    float* __restrict__ out) {
  __shared__ float p[128];
  int g = blockIdx.x, kq = blockIdx.y;
  int o = threadIdx.x;
  int cnt = gstart[g + 1] - gstart[g];
  float inv = 1.0f / fmaxf((float)cnt, 1.0f);
  p[o] = pooled[g * DD + kq * 128 + o] * inv;
  __syncthreads();
  float s = (kq == 0) ? blin[o] : 0.f;
#pragma unroll 8
  for (int k = 0; k < 128; ++k)
    s += p[k] * Wlin[(size_t)(kq * 128 + k) * OUTC + o];
  atomicAdd(&out[g * OUTC + o], s);
}

// ---------------- host ----------------
extern "C" void kernel_launch(void* const* d_in, const int* in_sizes, int n_in,
                              void* d_out, int out_size, void* d_ws, size_t ws_size,
                              hipStream_t stream) {
  const float* x_in = (const float*)d_in[0];
  const int* ei = (const int*)d_in[1];
  const int* src = ei;
  const int* dst = ei + EE;
  const int* batch = (const int*)d_in[2];
  WPtrs wp;
  const float* bias[5];
  for (int l = 0; l < 5; ++l) {
    wp.p[2 * l] = (const float*)d_in[3 + 3 * l];      // Wr
    wp.p[2 * l + 1] = (const float*)d_in[4 + 3 * l];  // Ws
    bias[l] = (const float*)d_in[5 + 3 * l];
  }
  const float* Wlin = (const float*)d_in[18];
  const float* blin = (const float*)d_in[19];
  float* out = (float*)d_out;

  char* ws = (char*)d_ws;
  size_t off = 0;
  auto alloc = [&](size_t bytes) { size_t o = off; off += (bytes + 511) & ~(size_t)511; return o; };
  float* xf = (float*)(ws + alloc((size_t)NN * DD * 4));
  unsigned short* m0 = (unsigned short*)(ws + alloc((size_t)NN * 1024 * 2));
  unsigned short* m1 = (unsigned short*)(ws + alloc((size_t)NN * 1024 * 2));
  unsigned short* wt = (unsigned short*)(ws + alloc((size_t)5 * DD * 1024 * 2));
  int* deg = (int*)(ws + alloc((size_t)NN * 4));
  int* offs = (int*)(ws + alloc((size_t)(NN + 1) * 4));
  int* fptr = (int*)(ws + alloc((size_t)NN * 4));
  int* ssrc = (int*)(ws + alloc((size_t)EE * 4));
  int* gstart = (int*)(ws + alloc((size_t)(GG + 1) * 4));
  float* pooled = (float*)(ws + alloc((size_t)GG * DD * 4));

  hipMemsetAsync(deg, 0, (size_t)NN * 4, stream);
  hipMemsetAsync(fptr, 0, (size_t)NN * 4, stream);
  hipMemsetAsync(pooled, 0, (size_t)GG * DD * 4, stream);
  hipMemsetAsync(out, 0, (size_t)GG * OUTC * 4, stream);

  // CSR
  int eblocks = (EE + 255) / 256;
  hist_dst<<<eblocks, 256, 0, stream>>>(dst, deg);
  scan_offsets<<<1, 1024, 0, stream>>>(deg, offs);
  fill_edges<<<eblocks, 256, 0, stream>>>(src, dst, offs, fptr, ssrc);

  // weights -> merged transposed bf16 (single dispatch)
  dim3 tb(32, 8), tg(DD / 32, DD / 32, 10);
  transpose_w_all<<<tg, tb, 0, stream>>>(wp, wt);

  // x -> fp32 master + bf16 right half of merged0
  convert_x<<<(NN * DD / 2 + 255) / 256, 256, 0, stream>>>(x_in, xf, m0);

  // graph boundaries (sorted batch, no atomics)
  graph_bounds<<<(NN + 255) / 256, 256, 0, stream>>>(batch, gstart);

  // layers
  dim3 ggrid((NN + 127) / 128, DD / 128);
  unsigned short* mc = m0;
  unsigned short* mn = m1;
  for (int l = 0; l < 5; ++l) {
    seg_sum<<<(NN + 3) / 4, 256, 0, stream>>>(mc, offs, ssrc);
    gemm_layer<<<ggrid, 256, 0, stream>>>(mc, wt + (size_t)l * DD * 1024,
                                          bias[l], xf, mn, l < 4 ? 1 : 0);
    unsigned short* t = mc; mc = mn; mn = t;
  }

  // pooling + final linear (mc == final merged buffer after 5 swaps)
  dim3 pgrid(GG, 8);
  pool_partial<<<pgrid, 256, 0, stream>>>(mc, gstart, pooled);
  dim3 fgrid(GG, 4);
  final_linear<<<fgrid, 128, 0, stream>>>(pooled, gstart, Wlin, blin, out);
}

// Round 4
// 283.501 us; speedup vs baseline: 2.8439x; 1.3881x over previous
//
#include <hip/hip_runtime.h>
#include <hip/hip_bf16.h>

#define NN 10000
#define EE 160000
#define DD 512
#define GG 64
#define OUTC 128

typedef __attribute__((ext_vector_type(8))) short bf16x8;
typedef __attribute__((ext_vector_type(4))) float f32x4;

static __device__ __forceinline__ unsigned short f2bf(float f) {
  unsigned u = __builtin_bit_cast(unsigned, f);
  unsigned rounding = 0x7fffu + ((u >> 16) & 1u);
  u += rounding;
  return (unsigned short)(u >> 16);
}
static __device__ __forceinline__ float bf2f(unsigned short h) {
  unsigned v = ((unsigned)h) << 16;
  return __builtin_bit_cast(float, v);
}

static __device__ __forceinline__ void gload_lds16(const void* g, void* l) {
  __builtin_amdgcn_global_load_lds(
      (const __attribute__((address_space(1))) unsigned*)g,
      (__attribute__((address_space(3))) unsigned*)l, 16, 0, 0);
}

// ---------------- CSR build ----------------
__global__ void hist_dst(const int* __restrict__ dst, int* __restrict__ cnt) {
  int e = blockIdx.x * 256 + threadIdx.x;
  if (e < EE) atomicAdd(&cnt[dst[e]], 1);
}

__global__ void scan_offsets(const int* __restrict__ cnt, int* __restrict__ offs) {
  __shared__ int wpre[17];
  __shared__ int carry;
  int t = threadIdx.x;            // 1024 threads = 16 waves
  int lane = t & 63, wv = t >> 6;
  if (t == 0) carry = 0;
  __syncthreads();
  for (int base = 0; base < NN; base += 1024) {
    int i = base + t;
    int v = (i < NN) ? cnt[i] : 0;
    int s = v;
#pragma unroll
    for (int d = 1; d < 64; d <<= 1) {
      int o = __shfl_up(s, d, 64);
      if (lane >= d) s += o;
    }
    if (lane == 63) wpre[wv] = s;
    __syncthreads();
    if (t == 0) {
      int r = 0;
      for (int w = 0; w < 16; ++w) { int x = wpre[w]; wpre[w] = r; r += x; }
      wpre[16] = r;
    }
    __syncthreads();
    int incl = s + wpre[wv] + carry;
    if (i < NN) offs[i] = incl - v;   // exclusive prefix
    __syncthreads();
    if (t == 0) carry += wpre[16];
    __syncthreads();
  }
  if (t == 0) offs[NN] = carry;       // == EE
}

__global__ void fill_edges(const int* __restrict__ src, const int* __restrict__ dst,
                           const int* __restrict__ offs, int* __restrict__ fptr,
                           int* __restrict__ ssrc) {
  int e = blockIdx.x * 256 + threadIdx.x;
  if (e < EE) {
    int d = dst[e];
    int p = atomicAdd(&fptr[d], 1);
    ssrc[offs[d] + p] = src[e];
  }
}

// ---------------- weight transpose + bf16 convert (all 10 in one dispatch) ----
// W [512 k][512 n] f32 row-major -> WT merged [layer][512 n][1024 k] bf16
// Wr occupies k 0..511, Ws occupies k 512..1023
struct WPtrs { const float* p[10]; };

__global__ void transpose_w_all(WPtrs wp, unsigned short* __restrict__ WT) {
  __shared__ float tile[32][33];
  int z = blockIdx.z;                 // 0..9: layer z>>1, (z&1)=Ws
  const float* W = wp.p[z];
  unsigned short* dst = WT + (size_t)(z >> 1) * DD * 1024 + (size_t)(z & 1) * DD;
  int bx = blockIdx.x * 32, by = blockIdx.y * 32;
  int tx = threadIdx.x, ty = threadIdx.y;
  for (int i = ty; i < 32; i += 8)
    tile[i][tx] = W[(size_t)(by + i) * DD + bx + tx];
  __syncthreads();
  for (int i = ty; i < 32; i += 8)
    dst[(size_t)(bx + i) * 1024 + by + tx] = f2bf(tile[tx][i]);
}

// ---------------- x convert: bf16 into merged0 right half ------
__global__ void convert_x(const float* __restrict__ x, unsigned short* __restrict__ m0) {
  int i = blockIdx.x * 256 + threadIdx.x;   // pair index
  if (i < NN * DD / 2) {
    float2 v = ((const float2*)x)[i];
    unsigned u = (unsigned)f2bf(v.x) | ((unsigned)f2bf(v.y) << 16);
    int e = i << 1;
    int row = e >> 9, col = e & 511;
    ((unsigned*)m0)[row * 512 + 256 + (col >> 1)] = u;
  }
}

// ---------------- segment sum: wave per node, 16B lanes, 8-edge ILP ----------
// merged layout per row: [agg(512) | x(512)] bf16.  Reads right half of
// gathered rows, writes left half of own row.
static __device__ __forceinline__ void acc8(float* a, uint4 v) {
  unsigned w0 = v.x, w1 = v.y, w2 = v.z, w3 = v.w;
  a[0] += __builtin_bit_cast(float, w0 << 16);
  a[1] += __builtin_bit_cast(float, w0 & 0xffff0000u);
  a[2] += __builtin_bit_cast(float, w1 << 16);
  a[3] += __builtin_bit_cast(float, w1 & 0xffff0000u);
  a[4] += __builtin_bit_cast(float, w2 << 16);
  a[5] += __builtin_bit_cast(float, w2 & 0xffff0000u);
  a[6] += __builtin_bit_cast(float, w3 << 16);
  a[7] += __builtin_bit_cast(float, w3 & 0xffff0000u);
}

__global__ __launch_bounds__(256) void seg_sum(unsigned short* __restrict__ merged,
                                               const int* __restrict__ offs,
                                               const int* __restrict__ ssrc) {
  int node = (blockIdx.x << 2) + (threadIdx.x >> 6);
  if (node >= NN) return;
  int lane = threadIdx.x & 63;
  int beg = offs[node], end = offs[node + 1];
  const uint4* xb = (const uint4*)merged;   // row = 128 uint4; right half at +64
  float a[8] = {0.f, 0.f, 0.f, 0.f, 0.f, 0.f, 0.f, 0.f};
  int e = beg;
  for (; e + 8 <= end; e += 8) {
    uint4 v0 = xb[(size_t)ssrc[e] * 128 + 64 + lane];
    uint4 v1 = xb[(size_t)ssrc[e + 1] * 128 + 64 + lane];
    uint4 v2 = xb[(size_t)ssrc[e + 2] * 128 + 64 + lane];
    uint4 v3 = xb[(size_t)ssrc[e + 3] * 128 + 64 + lane];
    uint4 v4 = xb[(size_t)ssrc[e + 4] * 128 + 64 + lane];
    uint4 v5 = xb[(size_t)ssrc[e + 5] * 128 + 64 + lane];
    uint4 v6 = xb[(size_t)ssrc[e + 6] * 128 + 64 + lane];
    uint4 v7 = xb[(size_t)ssrc[e + 7] * 128 + 64 + lane];
    acc8(a, v0); acc8(a, v1); acc8(a, v2); acc8(a, v3);
    acc8(a, v4); acc8(a, v5); acc8(a, v6); acc8(a, v7);
  }
  for (; e + 4 <= end; e += 4) {
    uint4 v0 = xb[(size_t)ssrc[e] * 128 + 64 + lane];
    uint4 v1 = xb[(size_t)ssrc[e + 1] * 128 + 64 + lane];
    uint4 v2 = xb[(size_t)ssrc[e + 2] * 128 + 64 + lane];
    uint4 v3 = xb[(size_t)ssrc[e + 3] * 128 + 64 + lane];
    acc8(a, v0); acc8(a, v1); acc8(a, v2); acc8(a, v3);
  }
  for (; e < end; ++e) {
    uint4 v = xb[(size_t)ssrc[e] * 128 + 64 + lane];
    acc8(a, v);
  }
  uint4 o;
  o.x = (unsigned)f2bf(a[0]) | ((unsigned)f2bf(a[1]) << 16);
  o.y = (unsigned)f2bf(a[2]) | ((unsigned)f2bf(a[3]) << 16);
  o.z = (unsigned)f2bf(a[4]) | ((unsigned)f2bf(a[5]) << 16);
  o.w = (unsigned)f2bf(a[6]) | ((unsigned)f2bf(a[7]) << 16);
  ((uint4*)merged)[(size_t)node * 128 + lane] = o;
}

// ---------------- fused layer GEMM --------------------------------------
// C[row,col] = sum_k merged[row][k] * WT[col][k]  (k 0..1023 = agg@Wr + x@Ws)
// then + bias + residual (bf16 x re-read from merged right half), ReLU,
// write bf16 into NEXT merged buffer's right half.  No fp32 master.
// Tile 64x128, BK=64, 4 waves (each 32x64), dbuf LDS via global_load_lds(16B),
// XOR chunk swizzle on global src AND ds_read (verified conflict-free r2/r3).
// Grid: 157*4 = 628 blocks, XCD-bijective swizzle (628 = 8*78+4).
__global__ __launch_bounds__(256) void gemm_layer(
    const unsigned short* __restrict__ Am,    // merged cur [NN][1024]
    const unsigned short* __restrict__ Bw,    // [512 n][1024 k]
    const float* __restrict__ bias,
    unsigned short* __restrict__ xout,        // merged next (write right half)
    int do_relu) {
  __shared__ unsigned short Al[2][64 * 64];
  __shared__ unsigned short Bl[2][128 * 64];
  int tid = threadIdx.x;
  int lane = tid & 63, wave = tid >> 6;
  int wr = wave >> 1, wc = wave & 1;        // wave tile 32 rows x 64 cols

  // bijective XCD swizzle: nwg=628, q=78, r=4 (m204)
  int orig = blockIdx.x;
  int xcd = orig & 7, cidx = orig >> 3;
  int wgid = (xcd < 4) ? xcd * 79 + cidx : 316 + (xcd - 4) * 78 + cidx;
  int brow = (wgid >> 2) * 64;
  int bcol = (wgid & 3) * 128;
  int lrow = lane & 15, lq = lane >> 4;

  f32x4 acc[2][4];
#pragma unroll
  for (int m = 0; m < 2; ++m)
#pragma unroll
    for (int n = 0; n < 4; ++n) acc[m][n] = (f32x4){0.f, 0.f, 0.f, 0.f};

  auto STAGE = [&](int buf, int t) {
    int k0 = t * 64;
#pragma unroll
    for (int i = 0; i < 2; ++i) {           // A: 64 rows x 8 chunks
      int idx = i * 256 + tid;
      int row = idx >> 3, c = idx & 7;
      int csw = (c ^ (row & 7)) * 8;
      int gr = brow + row;
      if (gr >= NN) gr = NN - 1;            // clamp; OOB rows never stored
      gload_lds16(Am + (size_t)gr * 1024 + k0 + csw, &Al[buf][idx * 8]);
    }
#pragma unroll
    for (int i = 0; i < 4; ++i) {           // B: 128 rows x 8 chunks
      int idx = i * 256 + tid;
      int row = idx >> 3, c = idx & 7;
      int csw = (c ^ (row & 7)) * 8;
      gload_lds16(Bw + (size_t)(bcol + row) * 1024 + k0 + csw, &Bl[buf][idx * 8]);
    }
  };

  STAGE(0, 0);
  __syncthreads();                            // buf0 ready
  int cur = 0;
#pragma unroll 1
  for (int t = 0; t < 16; ++t) {
    if (t < 15) STAGE(cur ^ 1, t + 1);        // in flight under compute
#pragma unroll
    for (int kk = 0; kk < 2; ++kk) {
      bf16x8 a[2], b[4];
      int lc = kk * 4 + lq;                   // logical 16B chunk 0..7
#pragma unroll
      for (int m = 0; m < 2; ++m) {
        int row = wr * 32 + m * 16 + lrow;
        a[m] = *(const bf16x8*)&Al[cur][row * 64 + ((lc ^ (lrow & 7)) * 8)];
      }
#pragma unroll
      for (int n = 0; n < 4; ++n) {
        int row = wc * 64 + n * 16 + lrow;
        b[n] = *(const bf16x8*)&Bl[cur][row * 64 + ((lc ^ (lrow & 7)) * 8)];
      }
#pragma unroll
      for (int m = 0; m < 2; ++m)
#pragma unroll
        for (int n = 0; n < 4; ++n)
          acc[m][n] = __builtin_amdgcn_mfma_f32_16x16x32_bf16(a[m], b[n], acc[m][n], 0, 0, 0);
    }
    __syncthreads();                          // compute done; next buf staged
    cur ^= 1;
  }

  // epilogue: C row=(lane>>4)*4+i, col=lane&15 within each 16x16 fragment
  int crow = (lane >> 4) * 4;
  int ccol = lane & 15;
#pragma unroll
  for (int m = 0; m < 2; ++m) {
#pragma unroll
    for (int n = 0; n < 4; ++n) {
      int col = bcol + wc * 64 + n * 16 + ccol;
      float bv = bias[col];
#pragma unroll
      for (int i = 0; i < 4; ++i) {
        int row = brow + wr * 32 + m * 16 + crow + i;
        if (row < NN) {
          size_t off = (size_t)row * 1024 + 512 + col;
          float v = acc[m][n][i] + bv + bf2f(Am[off]);   // bf16 residual
          if (do_relu) v = fmaxf(v, 0.f);
          xout[off] = f2bf(v);
        }
      }
    }
  }
}

// ---------------- pooling ----------------
// batch is sorted: find graph boundaries with disjoint writes (no atomics).
__global__ void graph_bounds(const int* __restrict__ batch, int* __restrict__ gstart) {
  int i = blockIdx.x * 256 + threadIdx.x;
  if (i >= NN) return;
  int cur = batch[i];
  int prev = (i == 0) ? -1 : batch[i - 1];
  for (int g = prev + 1; g <= cur; ++g) gstart[g] = i;
  if (i == NN - 1)
    for (int g = cur + 1; g <= GG; ++g) gstart[g] = NN;
}

// reads bf16 final x from merged right half
__global__ __launch_bounds__(256) void pool_partial(const unsigned short* __restrict__ mfin,
                                                    const int* __restrict__ gstart,
                                                    float* __restrict__ pooled) {
  int g = blockIdx.x, part = blockIdx.y;    // 8 parts per graph
  int t = threadIdx.x;                      // 256 threads: col pair 2t,2t+1
  int beg = gstart[g], end = gstart[g + 1];
  int n = end - beg;
  int per = (n + 7) >> 3;
  int b = beg + part * per;
  int e = b + per; if (e > end) e = end;
  if (b >= e) return;
  const unsigned* mw = (const unsigned*)mfin;
  float a0 = 0.f, a1 = 0.f;
  for (int r = b; r < e; ++r) {
    unsigned v = mw[(size_t)r * 512 + 256 + t];
    a0 += __builtin_bit_cast(float, v << 16);
    a1 += __builtin_bit_cast(float, v & 0xffff0000u);
  }
  atomicAdd(&pooled[g * DD + 2 * t], a0);
  atomicAdd(&pooled[g * DD + 2 * t + 1], a1);
}

// grid (GG, 4): each block computes 128-k-slice partial of out[g][*]
__global__ __launch_bounds__(128) void final_linear(const float* __restrict__ pooled,
                                                    const int* __restrict__ gstart,
                                                    const float* __restrict__ Wlin,
                                                    const float* __restrict__ blin,
                                                    float* __restrict__ out) {
  __shared__ float p[128];
  int g = blockIdx.x, kq = blockIdx.y;
  int o = threadIdx.x;
  int cnt = gstart[g + 1] - gstart[g];
  float inv = 1.0f / fmaxf((float)cnt, 1.0f);
  p[o] = pooled[g * DD + kq * 128 + o] * inv;
  __syncthreads();
  float s = (kq == 0) ? blin[o] : 0.f;
#pragma unroll 8
  for (int k = 0; k < 128; ++k)
    s += p[k] * Wlin[(size_t)(kq * 128 + k) * OUTC + o];
  atomicAdd(&out[g * OUTC + o], s);
}

// ---------------- host ----------------
extern "C" void kernel_launch(void* const* d_in, const int* in_sizes, int n_in,
                              void* d_out, int out_size, void* d_ws, size_t ws_size,
                              hipStream_t stream) {
  const float* x_in = (const float*)d_in[0];
  const int* ei = (const int*)d_in[1];
  const int* src = ei;
  const int* dst = ei + EE;
  const int* batch = (const int*)d_in[2];
  WPtrs wp;
  const float* bias[5];
  for (int l = 0; l < 5; ++l) {
    wp.p[2 * l] = (const float*)d_in[3 + 3 * l];      // Wr
    wp.p[2 * l + 1] = (const float*)d_in[4 + 3 * l];  // Ws
    bias[l] = (const float*)d_in[5 + 3 * l];
  }
  const float* Wlin = (const float*)d_in[18];
  const float* blin = (const float*)d_in[19];
  float* out = (float*)d_out;

  char* ws = (char*)d_ws;
  size_t off = 0;
  auto alloc = [&](size_t bytes) { size_t o = off; off += (bytes + 511) & ~(size_t)511; return o; };
  unsigned short* m0 = (unsigned short*)(ws + alloc((size_t)NN * 1024 * 2));
  unsigned short* m1 = (unsigned short*)(ws + alloc((size_t)NN * 1024 * 2));
  unsigned short* wt = (unsigned short*)(ws + alloc((size_t)5 * DD * 1024 * 2));
  int* deg = (int*)(ws + alloc((size_t)NN * 4));
  int* offs = (int*)(ws + alloc((size_t)(NN + 1) * 4));
  int* fptr = (int*)(ws + alloc((size_t)NN * 4));
  int* ssrc = (int*)(ws + alloc((size_t)EE * 4));
  int* gstart = (int*)(ws + alloc((size_t)(GG + 1) * 4));
  float* pooled = (float*)(ws + alloc((size_t)GG * DD * 4));

  hipMemsetAsync(deg, 0, (size_t)NN * 4, stream);
  hipMemsetAsync(fptr, 0, (size_t)NN * 4, stream);
  hipMemsetAsync(pooled, 0, (size_t)GG * DD * 4, stream);
  hipMemsetAsync(out, 0, (size_t)GG * OUTC * 4, stream);

  // CSR
  int eblocks = (EE + 255) / 256;
  hist_dst<<<eblocks, 256, 0, stream>>>(dst, deg);
  scan_offsets<<<1, 1024, 0, stream>>>(deg, offs);
  fill_edges<<<eblocks, 256, 0, stream>>>(src, dst, offs, fptr, ssrc);

  // weights -> merged transposed bf16 (single dispatch)
  dim3 tb(32, 8), tg(DD / 32, DD / 32, 10);
  transpose_w_all<<<tg, tb, 0, stream>>>(wp, wt);

  // x -> bf16 right half of merged0
  convert_x<<<(NN * DD / 2 + 255) / 256, 256, 0, stream>>>(x_in, m0);

  // graph boundaries (sorted batch, no atomics)
  graph_bounds<<<(NN + 255) / 256, 256, 0, stream>>>(batch, gstart);

  // layers
  unsigned short* mc = m0;
  unsigned short* mn = m1;
  for (int l = 0; l < 5; ++l) {
    seg_sum<<<(NN + 3) / 4, 256, 0, stream>>>(mc, offs, ssrc);
    gemm_layer<<<628, 256, 0, stream>>>(mc, wt + (size_t)l * DD * 1024,
                                        bias[l], mn, l < 4 ? 1 : 0);
    unsigned short* t = mc; mc = mn; mn = t;
  }

  // pooling + final linear (mc == final merged buffer after 5 swaps)
  dim3 pgrid(GG, 8);
  pool_partial<<<pgrid, 256, 0, stream>>>(mc, gstart, pooled);
  dim3 fgrid(GG, 4);
  final_linear<<<fgrid, 128, 0, stream>>>(pooled, gstart, Wlin, blin, out);
}